// Round 4
// baseline (291.331 us; speedup 1.0000x reference)
//
#include <hip/hip_runtime.h>
#include <hip/hip_bf16.h>

// out[c,n,o] = sum_i x[c,n,i] * W[model_idx[c],i,o] + B[int(t[c]*31),o]
// x[64,2048,256] f32, t[64] f32, model_idx[64] i32, W[64,256,256] f32,
// B[32,256] f32, out f32. Internal math bf16 MFMA (2% threshold allows it;
// round-3 passed at absmax 1.6e-2).
//
// Round-4 structure: W panel transposed to bf16 LDS once per block (one
// barrier); A-fragments loaded DIRECTLY from global X into registers
// (fragment layout A[m=lane&15][k=(lane>>4)*8+j] == two float4 per frag).
// K-loop has NO barriers -> per-wave MLP hides HBM latency instead of
// block-wide vmcnt(0) drains (round-3 was latency-bound: 2.9 TB/s, all
// pipes <20%).

#define M_PTS 2048
#define K_DIM 256
#define N_DIM 256
#define BT_STRIDE 264  // 256+8 pad; 264*2=528 B keeps 16B alignment for b128 reads

typedef float floatx4 __attribute__((ext_vector_type(4)));
typedef __bf16 bf16x4 __attribute__((ext_vector_type(4)));
typedef __bf16 bf16x8 __attribute__((ext_vector_type(8)));

__device__ __forceinline__ __bf16 cvt_bf16(float f) {
  // round-to-nearest-even f32 -> bf16 (finite inputs), branch-free
  unsigned u = __builtin_bit_cast(unsigned, f);
  unsigned r = (u + 0x7FFFu + ((u >> 16) & 1u)) >> 16;
  return __builtin_bit_cast(__bf16, (unsigned short)r);
}

__global__ __launch_bounds__(256) void fused_k(
    const float* __restrict__ X, const float* __restrict__ T,
    const int* __restrict__ MI, const float* __restrict__ W,
    const float* __restrict__ Bb, float* __restrict__ Out) {
  __shared__ __bf16 Bt[128 * BT_STRIDE];  // W^T panel [n=128][k=256], 67.6 KB

  const int bid = blockIdx.x;      // 1024 blocks
  const int c   = bid >> 4;        // channel (64)
  const int mg  = (bid >> 1) & 7;  // 256-row m-group (8)
  const int nt  = bid & 1;         // n-half (2); twins adjacent -> X L2 reuse
  const int n0  = nt * 128;

  const float* __restrict__ Xc = X + (size_t)c * (M_PTS * K_DIM);
  const float* __restrict__ Wc = W + (size_t)MI[c] * (K_DIM * N_DIM);

  const int tid  = threadIdx.x;
  const int lane = tid & 63;
  const int w    = tid >> 6;
  const int wm   = w & 1;      // 2x2 wave grid
  const int wn   = w >> 1;
  const int r    = lane & 15;  // fragment row/col
  const int kg   = lane >> 4;  // k-group 0..3

  // ---- one-time: Bt[n][k] = bf16(Wc[k][n0+n]) ----------------------------
  // lanes take consecutive n -> coalesced 256B global segments per wave-read
  {
    const int n  = tid & 127;
    const int kq = tid >> 7;  // k-half
    const float* __restrict__ src = Wc + (size_t)(kq * 128) * N_DIM + n0 + n;
    __bf16* __restrict__ dst = &Bt[n * BT_STRIDE + kq * 128];
#pragma unroll 4
    for (int u = 0; u < 32; ++u) {
      bf16x4 v;
      v.x = cvt_bf16(src[(size_t)(u * 4 + 0) * N_DIM]);
      v.y = cvt_bf16(src[(size_t)(u * 4 + 1) * N_DIM]);
      v.z = cvt_bf16(src[(size_t)(u * 4 + 2) * N_DIM]);
      v.w = cvt_bf16(src[(size_t)(u * 4 + 3) * N_DIM]);
      *(bf16x4*)&dst[u * 4] = v;  // 8B store, k-contiguous
    }
  }

  // ---- bias (fp32, exact): idx = trunc(t[c]*31) --------------------------
  int bidx = (int)(T[c] * 31.0f);
  bidx = bidx < 0 ? 0 : (bidx > 31 ? 31 : bidx);
  const float* __restrict__ brow = Bb + bidx * N_DIM + n0 + wn * 64;
  float bv[4];
#pragma unroll
  for (int j = 0; j < 4; ++j) bv[j] = brow[j * 16 + r];

  __syncthreads();  // Bt visible to all waves; the ONLY barrier in the kernel

  float* __restrict__ Oc = Out + (size_t)c * (M_PTS * N_DIM);

  for (int mt2 = 0; mt2 < 2; ++mt2) {
    const int m0 = mg * 256 + mt2 * 128;
    // this lane's A rows: m0 + wm*64 + i*16 + r, k chunk at kg*8
    const float* __restrict__ xbase =
        Xc + (size_t)(m0 + wm * 64 + r) * K_DIM + kg * 8;

    floatx4 acc[4][4];
#pragma unroll
    for (int i = 0; i < 4; ++i)
#pragma unroll
      for (int j = 0; j < 4; ++j)
        acc[i][j] = (floatx4){bv[j], bv[j], bv[j], bv[j]};  // bias as C-init

#pragma unroll 2
    for (int kt = 0; kt < 8; ++kt) {
      const int k0 = kt * 32;
      bf16x8 a[4], b[4];
#pragma unroll
      for (int i = 0; i < 4; ++i) {
        const float* p = xbase + (size_t)i * 16 * K_DIM + k0;
        floatx4 f0 = *(const floatx4*)(p);
        floatx4 f1 = *(const floatx4*)(p + 4);
#pragma unroll
        for (int v = 0; v < 4; ++v) {
          a[i][v]     = cvt_bf16(f0[v]);
          a[i][v + 4] = cvt_bf16(f1[v]);
        }
      }
#pragma unroll
      for (int j = 0; j < 4; ++j)
        b[j] = *(const bf16x8*)&Bt[(wn * 64 + j * 16 + r) * BT_STRIDE + k0 + kg * 8];
#pragma unroll
      for (int i = 0; i < 4; ++i)
#pragma unroll
        for (int j = 0; j < 4; ++j)
          acc[i][j] = __builtin_amdgcn_mfma_f32_16x16x32_bf16(a[i], b[j], acc[i][j], 0, 0, 0);
    }

    // ---- epilogue: C/D layout col=lane&15, row=(lane>>4)*4+reg [m89/m91] --
#pragma unroll
    for (int i = 0; i < 4; ++i) {
#pragma unroll
      for (int j = 0; j < 4; ++j) {
        const int col = n0 + wn * 64 + j * 16 + r;
#pragma unroll
        for (int v = 0; v < 4; ++v) {
          const int row = m0 + wm * 64 + i * 16 + kg * 4 + v;
          Oc[(size_t)row * N_DIM + col] = acc[i][j][v];
        }
      }
    }
  }
}

extern "C" void kernel_launch(void* const* d_in, const int* in_sizes, int n_in,
                              void* d_out, int out_size, void* d_ws, size_t ws_size,
                              hipStream_t stream) {
  const float* X   = (const float*)d_in[0];  // x [64,2048,256]
  const float* T   = (const float*)d_in[1];  // t [64]
  const int* MI    = (const int*)d_in[2];    // model_idx [64]
  const float* W   = (const float*)d_in[3];  // W [64,256,256]
  const float* Bb  = (const float*)d_in[4];  // B [32,256]
  float* Out       = (float*)d_out;

  fused_k<<<dim3(1024), dim3(256), 0, stream>>>(X, T, MI, W, Bb, Out);
}